// Round 19
// baseline (41.673 us; speedup 1.0000x reference)
//
#include <hip/hip_runtime.h>

#define DD 1024
#define HALO 32
#define IMGF (2 * (HALO + DD + HALO))   // floats per interleaved row image = 2176 = 17*128
#define NJ 2                             // row-pair jobs per block (grid = jobs / NJ)
// K=2 minimax-Cayley (validated r17, absmax 0.03125 == noise floor):
//   y1 = rot + C1*(H rot)^perp ; x = rot + C2*(H y1)^perp
//   C1 = (c2/c1)*h = 0.0498693, C2 = -c1*h = 0.0975700  (h = dt/2)
#define C1_F 0.0498693f
#define C2_F 0.0975700f

typedef float f2 __attribute__((ext_vector_type(2)));   // (re, im) -> VGPR pair

// d -= w * v, w = uniform SGPR pair {w,w} (forced VOP3P packed FMA)
__device__ __forceinline__ void pk_fnma_s(f2& d, unsigned long long w, f2 v) {
    asm("v_pk_fma_f32 %0, %1, %2, %0 neg_lo:[1,0,0] neg_hi:[1,0,0]"
        : "+v"(d) : "s"(w), "v"(v));
}

// XOR swizzle on float index. Involution; preserves 16B alignment; commutes
// with multiples of 128 floats: IMGF buffer stride, row stride, +-2*DD halo.
__device__ __forceinline__ int swzf(int f) { return f ^ (((f >> 5) & 3) << 2); }

// Wave64 sum via DPP. Total valid in lane 63 ONLY.
__device__ __forceinline__ float dpp_wave_sum(float v) {
    int b;
    b = __builtin_amdgcn_update_dpp(0, __float_as_int(v), 0x111, 0xf, 0xf, true); v += __int_as_float(b);
    b = __builtin_amdgcn_update_dpp(0, __float_as_int(v), 0x112, 0xf, 0xf, true); v += __int_as_float(b);
    b = __builtin_amdgcn_update_dpp(0, __float_as_int(v), 0x114, 0xf, 0xf, true); v += __int_as_float(b);
    b = __builtin_amdgcn_update_dpp(0, __float_as_int(v), 0x118, 0xf, 0xf, true); v += __int_as_float(b);
    b = __builtin_amdgcn_update_dpp(0, __float_as_int(v), 0x142, 0xa, 0xf, true); v += __int_as_float(b);
    b = __builtin_amdgcn_update_dpp(0, __float_as_int(v), 0x143, 0xc, 0xf, true); v += __int_as_float(b);
    return v;
}

// Row-wide (128-thread, 2-wave) sum; exactly one barrier.
// Cross-job red0 reuse is safe: job j's read (post-B0) precedes its B1; any
// thread's job-j+1 write happens after passing job-j B2 => all B1-crossers
// (hence all job-j reads) are done.
__device__ __forceinline__ float row_sum(float v, float* red, int wave, int rw) {
    v = dpp_wave_sum(v);
    if ((threadIdx.x & 63) == 63) red[wave] = v;
    __syncthreads();
    return red[2 * rw] + red[2 * rw + 1];
}

// Packed H-apply on this thread's 8 complex elements (center in regs);
// cOff = compile-time buffer offset (0 or IMGF) -> folds into ds immediates.
__device__ __forceinline__ void hmat8p(const float* lds, const int raL[10], const int raR[10],
                                       int cOff, const unsigned long long wp[11],
                                       const float diag[8], const f2 pc[8], f2 H[8]) {
    constexpr int taps[11] = {1, 2, 3, 4, 5, 6, 8, 10, 12, 16, 20};
    {   // pass L: left 20 complex + all center-resident taps
        f2 lw[20];
#pragma unroll
        for (int k = 0; k < 10; ++k) {
            float4 v = *reinterpret_cast<const float4*>(&lds[raL[k] + cOff]);
            lw[2 * k] = f2{v.x, v.y};
            lw[2 * k + 1] = f2{v.z, v.w};
        }
#pragma unroll
        for (int i = 0; i < 8; ++i) {
            f2 acc = f2{diag[i] * pc[i].x, diag[i] * pc[i].y};
#pragma unroll
            for (int j = 0; j < 11; ++j) {
                const int n = i - taps[j];
                pk_fnma_s(acc, wp[j], (n >= 0) ? pc[n] : lw[20 + n]);
                const int m = i + taps[j];
                if (m <= 7) pk_fnma_s(acc, wp[j], pc[m]);
            }
            H[i] = acc;
        }
    }
    {   // pass R: right 20 complex
        f2 rw2[20];
#pragma unroll
        for (int k = 0; k < 10; ++k) {
            float4 v = *reinterpret_cast<const float4*>(&lds[raR[k] + cOff]);
            rw2[2 * k] = f2{v.x, v.y};
            rw2[2 * k + 1] = f2{v.z, v.w};
        }
#pragma unroll
        for (int i = 0; i < 8; ++i) {
#pragma unroll
            for (int j = 0; j < 11; ++j) {
                const int m = i + taps[j];
                if (m > 7) pk_fnma_s(H[i], wp[j], rw2[m - 8]);
            }
        }
    }
}

// Store this thread's 8 interleaved complex (4 float4) + halo copies.
__device__ __forceinline__ void store_row8p(float* lds, const int wa[4], const int ha[4],
                                            int cOff, bool hh, const f2 v[8]) {
#pragma unroll
    for (int j = 0; j < 4; ++j) {
        float4 a = make_float4(v[2 * j].x, v[2 * j].y, v[2 * j + 1].x, v[2 * j + 1].y);
        *reinterpret_cast<float4*>(&lds[wa[j] + cOff]) = a;
        if (hh) *reinterpret_cast<float4*>(&lds[ha[j] + cOff]) = a;
    }
}

__global__ void __launch_bounds__(256, 2)
cayley_kernel(const float* __restrict__ psi_r, const float* __restrict__ psi_i,
              const float* __restrict__ alpha, const float* __restrict__ sw,
              const float* __restrict__ potential, float* __restrict__ out) {
    // 2 rows x 2 buffered images, interleaved complex.
    __shared__ __align__(16) float lds[4 * IMGF];
    __shared__ float red0[4];

    const int t = threadIdx.x;
    const int u = t & 127;         // row-local thread: owns complex [8u, 8u+8)
    const int rw = t >> 7;         // row within block (0/1)
    const int wave = t >> 6;
    const int rb = rw * (2 * IMGF);   // row base: two buffers per row

    // ---- job-invariant setup (amortized over NJ jobs) ----
    const float w0 = sw[0], w1 = sw[1], w2 = sw[2];
    const float cwv[11] = {w0, w0 + w1, w0, w0 + w1 + w2, w0, w1, w1 + w2, w1, w2, w2, w2};
    const float dadd = 10.0f * (w0 + w1 + w2);

    unsigned long long wp[11];
#pragma unroll
    for (int j = 0; j < 11; ++j) {
        const unsigned int b = __builtin_amdgcn_readfirstlane(__float_as_uint(cwv[j]));
        wp[j] = ((unsigned long long)b << 32) | b;
    }

    const int fb = rb + 2 * (HALO + 8 * u);
    int wa[4], raL[10], raR[10];
#pragma unroll
    for (int j = 0; j < 4; ++j) wa[j] = swzf(fb + 4 * j);
#pragma unroll
    for (int k = 0; k < 10; ++k) {
        raL[k] = swzf(fb - 40 + 4 * k);       // left 20 complex
        raR[k] = swzf(fb + 16 + 4 * k);       // right 20 complex
    }
    const bool hh = (u < 4) || (u >= 124);
    int ha[4] = {0, 0, 0, 0};
    if (u < 4) {
#pragma unroll
        for (int j = 0; j < 4; ++j) ha[j] = swzf(fb + 2 * DD + 4 * j);
    } else if (u >= 124) {
#pragma unroll
        for (int j = 0; j < 4; ++j) ha[j] = swzf(fb - 2 * DD + 4 * j);
    }

    float diag[8], alv[8];
#pragma unroll
    for (int j = 0; j < 2; ++j) {
        float4 d = *reinterpret_cast<const float4*>(potential + 8 * u + 4 * j);
        float4 c = *reinterpret_cast<const float4*>(alpha + 8 * u + 4 * j);
        diag[4 * j] = d.x + dadd; diag[4 * j + 1] = d.y + dadd;
        diag[4 * j + 2] = d.z + dadd; diag[4 * j + 3] = d.w + dadd;
        alv[4 * j] = c.x; alv[4 * j + 1] = c.y;
        alv[4 * j + 2] = c.z; alv[4 * j + 3] = c.w;
    }

    // ---- job 0 psi load ----
    size_t goff = ((size_t)(2 * blockIdx.x) + rw) * DD + 8 * u;
    f2 cur[8];
#pragma unroll
    for (int j = 0; j < 2; ++j) {
        float4 a = *reinterpret_cast<const float4*>(psi_r + goff + 4 * j);
        float4 b = *reinterpret_cast<const float4*>(psi_i + goff + 4 * j);
        cur[4 * j + 0] = f2{a.x, b.x};
        cur[4 * j + 1] = f2{a.y, b.y};
        cur[4 * j + 2] = f2{a.z, b.z};
        cur[4 * j + 3] = f2{a.w, b.w};
    }

#pragma unroll
    for (int jb = 0; jb < NJ; ++jb) {
        // --- intensity mean over the row ---
        float isum = 0.f;
#pragma unroll
        for (int i = 0; i < 8; ++i) isum += cur[i].x * cur[i].x + cur[i].y * cur[i].y;
        const float tot = row_sum(isum, red0, wave, rw);   // B0
        const float inv_mean = 1.0f / (tot * (1.0f / DD) + 1e-8f);

        // --- nonlinear phase rotation (in place; cur := rot) ---
#pragma unroll
        for (int i = 0; i < 8; ++i) {
            const float ph = alv[i] * ((cur[i].x * cur[i].x + cur[i].y * cur[i].y) * inv_mean);
            float s, cc;
            __sincosf(ph, &s, &cc);
            cur[i] = f2{cur[i].x * cc - cur[i].y * s, cur[i].x * s + cur[i].y * cc};
        }

        // step 1 store (buf0). B0 of this job fenced the previous job's buf0 reads.
        store_row8p(lds, wa, ha, 0, hh, cur);

        // --- prefetch next job's psi: issue before B1, consume next loop top;
        // latency hides under this job's two matvecs. ---
        float4 na0, nb0, na1, nb1;
        size_t goff_n = 0;
        if (jb + 1 < NJ) {
            goff_n = ((size_t)(2 * (blockIdx.x + (jb + 1) * gridDim.x)) + rw) * DD + 8 * u;
            na0 = *reinterpret_cast<const float4*>(psi_r + goff_n);
            nb0 = *reinterpret_cast<const float4*>(psi_i + goff_n);
            na1 = *reinterpret_cast<const float4*>(psi_r + goff_n + 4);
            nb1 = *reinterpret_cast<const float4*>(psi_i + goff_n + 4);
        }

        __syncthreads();                                   // B1: rot visible
        f2 y[8], Hy[8];
        hmat8p(lds, raL, raR, 0, wp, diag, cur, Hy);
#pragma unroll
        for (int i = 0; i < 8; ++i)
            y[i] = f2{cur[i].x + C1_F * Hy[i].y, cur[i].y - C1_F * Hy[i].x};

        store_row8p(lds, wa, ha, IMGF, hh, y);             // buf1 (prev-job buf1 reads fenced by B0+B1)
        __syncthreads();                                   // B2: y1 visible
        hmat8p(lds, raL, raR, IMGF, wp, diag, y, Hy);

        // --- x = rot + C2*(H y1)^perp; write out ---
        float* op = out + 2 * goff;
#pragma unroll
        for (int j = 0; j < 4; ++j) {
            const f2 x0 = f2{cur[2 * j].x + C2_F * Hy[2 * j].y,
                             cur[2 * j].y - C2_F * Hy[2 * j].x};
            const f2 x1 = f2{cur[2 * j + 1].x + C2_F * Hy[2 * j + 1].y,
                             cur[2 * j + 1].y - C2_F * Hy[2 * j + 1].x};
            *reinterpret_cast<float4*>(op + 4 * j) = make_float4(x0.x, x0.y, x1.x, x1.y);
        }

        // --- rotate prefetched psi into cur for the next job ---
        if (jb + 1 < NJ) {
            cur[0] = f2{na0.x, nb0.x}; cur[1] = f2{na0.y, nb0.y};
            cur[2] = f2{na0.z, nb0.z}; cur[3] = f2{na0.w, nb0.w};
            cur[4] = f2{na1.x, nb1.x}; cur[5] = f2{na1.y, nb1.y};
            cur[6] = f2{na1.z, nb1.z}; cur[7] = f2{na1.w, nb1.w};
            goff = goff_n;
        }
    }
}

extern "C" void kernel_launch(void* const* d_in, const int* in_sizes, int n_in,
                              void* d_out, int out_size, void* d_ws, size_t ws_size,
                              hipStream_t stream) {
    const float* psi_r = (const float*)d_in[0];
    const float* psi_i = (const float*)d_in[1];
    const float* alpha = (const float*)d_in[2];
    const float* sw = (const float*)d_in[3];
    const float* pot = (const float*)d_in[4];
    float* out = (float*)d_out;
    const int rows = in_sizes[0] / DD;        // B*S = 8192
    const int jobs = rows / 2;                // 4096 row-pairs
    cayley_kernel<<<dim3(jobs / NJ), dim3(256), 0, stream>>>(psi_r, psi_i, alpha, sw, pot, out);
}

// Round 20
// 40.494 us; speedup vs baseline: 1.0291x; 1.0291x over previous
//
#include <hip/hip_runtime.h>

#define DD 1024
#define IMGF 2176                 // row image floats: [0,40) Lhalo | [40,2088) row | [2088,2128) Rhalo | pad
// K=2 minimax-Cayley (validated r17): y1 = rot + C1*(H rot)^perp ; x = rot + C2*(H y1)^perp
#define C1_F 0.0498693f
#define C2_F 0.0975700f

typedef float f2 __attribute__((ext_vector_type(2)));

// d -= w * v, w = uniform SGPR pair {w,w} (forced VOP3P packed FMA)
__device__ __forceinline__ void pk_fnma_s(f2& d, unsigned long long w, f2 v) {
    asm("v_pk_fma_f32 %0, %1, %2, %0 neg_lo:[1,0,0] neg_hi:[1,0,0]"
        : "+v"(d) : "s"(w), "v"(v));
}

// XOR swizzle (r17-validated): involution, 16B-align preserved, commutes with
// multiples of 128 floats (chunk1 +1024, halos +-2048/-1024, row base IMGF... all OK:
// offsets used are +-1024/+2048, multiples of 128 ✓).
__device__ __forceinline__ int swzf(int f) { return f ^ (((f >> 5) & 3) << 2); }

__device__ __forceinline__ void fence_lds() {
    asm volatile("s_waitcnt lgkmcnt(0)" ::: "memory");
}

// Wave64 sum via DPP; total in lane 63, broadcast via readlane (no barrier).
__device__ __forceinline__ float wave_total(float v) {
    int b;
    b = __builtin_amdgcn_update_dpp(0, __float_as_int(v), 0x111, 0xf, 0xf, true); v += __int_as_float(b);
    b = __builtin_amdgcn_update_dpp(0, __float_as_int(v), 0x112, 0xf, 0xf, true); v += __int_as_float(b);
    b = __builtin_amdgcn_update_dpp(0, __float_as_int(v), 0x114, 0xf, 0xf, true); v += __int_as_float(b);
    b = __builtin_amdgcn_update_dpp(0, __float_as_int(v), 0x118, 0xf, 0xf, true); v += __int_as_float(b);
    b = __builtin_amdgcn_update_dpp(0, __float_as_int(v), 0x142, 0xa, 0xf, true); v += __int_as_float(b);
    b = __builtin_amdgcn_update_dpp(0, __float_as_int(v), 0x143, 0xc, 0xf, true); v += __int_as_float(b);
    return __int_as_float(__builtin_amdgcn_readlane(__float_as_int(v), 63));
}

// tap -> weight index, -1 if none. Constant-folds under full unroll.
__device__ constexpr int tapidx(int a) {
    return a == 1 ? 0 : a == 2 ? 1 : a == 3 ? 2 : a == 4 ? 3 : a == 5 ? 4 :
           a == 6 ? 5 : a == 8 ? 6 : a == 10 ? 7 : a == 12 ? 8 :
           a == 16 ? 9 : a == 20 ? 10 : -1;
}

// Scatter-accumulate H on one 8-complex chunk (centers from regs, neighbors
// streamed from LDS 1 b128 at a time -> ~4-reg transient window).
__device__ __forceinline__ void hmat8s(const float* lds, const int raL[10], const int raR[10],
                                       int cOff, const unsigned long long wp[11],
                                       const float* diag, const f2* pc, f2* H) {
    constexpr int taps[11] = {1, 2, 3, 4, 5, 6, 8, 10, 12, 16, 20};
#pragma unroll
    for (int i = 0; i < 8; ++i) {
        f2 acc = f2{diag[i] * pc[i].x, diag[i] * pc[i].y};
#pragma unroll
        for (int j = 0; j < 11; ++j) {              // center-resident taps
            const int n = i - taps[j];
            if (n >= 0) pk_fnma_s(acc, wp[j], pc[n]);
            const int m = i + taps[j];
            if (m <= 7) pk_fnma_s(acc, wp[j], pc[m]);
        }
        H[i] = acc;
    }
#pragma unroll
    for (int k = 0; k < 10; ++k) {                  // left window, complex -20+2k
        float4 q = *reinterpret_cast<const float4*>(&lds[raL[k] + cOff]);
        f2 c0 = f2{q.x, q.y}, c1 = f2{q.z, q.w};
#pragma unroll
        for (int i = 0; i < 8; ++i) {
            const int a0 = i + 20 - 2 * k, a1 = a0 - 1;
            if (tapidx(a0) >= 0) pk_fnma_s(H[i], wp[tapidx(a0)], c0);
            if (a1 >= 1 && tapidx(a1) >= 0) pk_fnma_s(H[i], wp[tapidx(a1)], c1);
        }
    }
#pragma unroll
    for (int k = 0; k < 10; ++k) {                  // right window, complex 8+2k
        float4 q = *reinterpret_cast<const float4*>(&lds[raR[k] + cOff]);
        f2 c0 = f2{q.x, q.y}, c1 = f2{q.z, q.w};
#pragma unroll
        for (int i = 0; i < 8; ++i) {
            const int a0 = 8 + 2 * k - i, a1 = a0 + 1;
            if (tapidx(a0) >= 0) pk_fnma_s(H[i], wp[tapidx(a0)], c0);
            if (tapidx(a1) >= 0) pk_fnma_s(H[i], wp[tapidx(a1)], c1);
        }
    }
}

__global__ void __launch_bounds__(256, 2)
cayley_kernel(const float* __restrict__ psi_r, const float* __restrict__ psi_i,
              const float* __restrict__ alpha, const float* __restrict__ sw,
              const float* __restrict__ potential, float* __restrict__ out) {
    __shared__ __align__(16) float lds[4 * IMGF];   // 4 independent waves, 1 row each

    const int l = threadIdx.x & 63;
    const int wv = threadIdx.x >> 6;
    const int row = (blockIdx.x << 2) + wv;
    const int ib = wv * IMGF;

    const float w0 = sw[0], w1 = sw[1], w2 = sw[2];
    const float cwv[11] = {w0, w0 + w1, w0, w0 + w1 + w2, w0, w1, w1 + w2, w1, w2, w2, w2};
    const float dadd = 10.0f * (w0 + w1 + w2);

    unsigned long long wp[11];
#pragma unroll
    for (int j = 0; j < 11; ++j) {
        const unsigned int b = __builtin_amdgcn_readfirstlane(__float_as_uint(cwv[j]));
        wp[j] = ((unsigned long long)b << 32) | b;
    }

    // Addresses (float idx). Chunk0 windows; chunk1 = +1024 imm (swizzle commutes).
    const int fl = ib + 16 * l;
    int wa[4], raL[10], raR[10];
#pragma unroll
    for (int j = 0; j < 4; ++j) wa[j] = swzf(fl + 40 + 4 * j);
#pragma unroll
    for (int k = 0; k < 5; ++k) {
        raL[k] = swzf(fl + 4 * k);            raL[5 + k] = swzf(fl + 20 + 4 * k);
        raR[k] = swzf(fl + 56 + 4 * k);       raR[5 + k] = swzf(fl + 76 + 4 * k);
    }
    const int jminL = (l == 61) ? 2 : 0;                       // left halo: lanes 61..63 (chunk1)
    const int jmaxR = (l < 2) ? 4 : ((l == 2) ? 2 : 0);        // right halo: lanes 0..2 (chunk0)

    // --- global loads: chunk0 = [8l,8l+8), chunk1 = +512 complex ---
    const size_t g0 = (size_t)row * DD + 8 * l;
    f2 cur[16];
    float diag[16], alv[16];
#pragma unroll
    for (int c = 0; c < 2; ++c) {
        const size_t g = g0 + 512 * c;
#pragma unroll
        for (int j = 0; j < 2; ++j) {
            float4 a = *reinterpret_cast<const float4*>(psi_r + g + 4 * j);
            float4 b = *reinterpret_cast<const float4*>(psi_i + g + 4 * j);
            float4 d = *reinterpret_cast<const float4*>(potential + 8 * l + 512 * c + 4 * j);
            float4 e = *reinterpret_cast<const float4*>(alpha + 8 * l + 512 * c + 4 * j);
            const int o = 8 * c + 4 * j;
            cur[o + 0] = f2{a.x, b.x}; cur[o + 1] = f2{a.y, b.y};
            cur[o + 2] = f2{a.z, b.z}; cur[o + 3] = f2{a.w, b.w};
            diag[o] = d.x + dadd; diag[o + 1] = d.y + dadd;
            diag[o + 2] = d.z + dadd; diag[o + 3] = d.w + dadd;
            alv[o] = e.x; alv[o + 1] = e.y; alv[o + 2] = e.z; alv[o + 3] = e.w;
        }
    }

    // --- intensity mean: pure wave reduction, NO barrier ---
    float isum = 0.f;
#pragma unroll
    for (int i = 0; i < 16; ++i) isum += cur[i].x * cur[i].x + cur[i].y * cur[i].y;
    const float inv_mean = 1.0f / (wave_total(isum) * (1.0f / DD) + 1e-8f);

    // --- nonlinear phase rotation (in place) ---
#pragma unroll
    for (int i = 0; i < 16; ++i) {
        const float ph = alv[i] * ((cur[i].x * cur[i].x + cur[i].y * cur[i].y) * inv_mean);
        float s, cc;
        __sincosf(ph, &s, &cc);
        cur[i] = f2{cur[i].x * cc - cur[i].y * s, cur[i].x * s + cur[i].y * cc};
    }

    // --- publish rot (both chunks + halos); wave-private fence only ---
#pragma unroll
    for (int j = 0; j < 4; ++j) {
        float4 a0 = make_float4(cur[2 * j].x, cur[2 * j].y, cur[2 * j + 1].x, cur[2 * j + 1].y);
        float4 a1 = make_float4(cur[8 + 2 * j].x, cur[8 + 2 * j].y, cur[9 + 2 * j].x, cur[9 + 2 * j].y);
        *reinterpret_cast<float4*>(&lds[wa[j]]) = a0;
        *reinterpret_cast<float4*>(&lds[wa[j] + 1024]) = a1;
        if (l >= 61 && j >= jminL) *reinterpret_cast<float4*>(&lds[wa[j] - 1024]) = a1;
        if (j < jmaxR)             *reinterpret_cast<float4*>(&lds[wa[j] + 2048]) = a0;
    }
    fence_lds();

    // --- matvec 1: H(rot); y1 = rot + C1*H^perp ---
    f2 y[16], H[16];
    hmat8s(lds, raL, raR, 0,    wp, diag,     cur,     H);
    hmat8s(lds, raL, raR, 1024, wp, diag + 8, cur + 8, H + 8);
#pragma unroll
    for (int i = 0; i < 16; ++i)
        y[i] = f2{cur[i].x + C1_F * H[i].y, cur[i].y - C1_F * H[i].x};

    // --- publish y1 (overwrites rot; DS ops in-order per wave => no WAR) ---
#pragma unroll
    for (int j = 0; j < 4; ++j) {
        float4 a0 = make_float4(y[2 * j].x, y[2 * j].y, y[2 * j + 1].x, y[2 * j + 1].y);
        float4 a1 = make_float4(y[8 + 2 * j].x, y[8 + 2 * j].y, y[9 + 2 * j].x, y[9 + 2 * j].y);
        *reinterpret_cast<float4*>(&lds[wa[j]]) = a0;
        *reinterpret_cast<float4*>(&lds[wa[j] + 1024]) = a1;
        if (l >= 61 && j >= jminL) *reinterpret_cast<float4*>(&lds[wa[j] - 1024]) = a1;
        if (j < jmaxR)             *reinterpret_cast<float4*>(&lds[wa[j] + 2048]) = a0;
    }
    fence_lds();

    // --- matvec 2: H(y1); x = rot + C2*H^perp; write out ---
    hmat8s(lds, raL, raR, 0,    wp, diag,     y,     H);
    hmat8s(lds, raL, raR, 1024, wp, diag + 8, y + 8, H + 8);

    float* op = out + 2 * g0;
#pragma unroll
    for (int c = 0; c < 2; ++c) {
#pragma unroll
        for (int j = 0; j < 4; ++j) {
            const int o = 8 * c + 2 * j;
            const f2 x0 = f2{cur[o].x + C2_F * H[o].y, cur[o].y - C2_F * H[o].x};
            const f2 x1 = f2{cur[o + 1].x + C2_F * H[o + 1].y, cur[o + 1].y - C2_F * H[o + 1].x};
            *reinterpret_cast<float4*>(op + 1024 * c + 4 * j) = make_float4(x0.x, x0.y, x1.x, x1.y);
        }
    }
}

extern "C" void kernel_launch(void* const* d_in, const int* in_sizes, int n_in,
                              void* d_out, int out_size, void* d_ws, size_t ws_size,
                              hipStream_t stream) {
    const float* psi_r = (const float*)d_in[0];
    const float* psi_i = (const float*)d_in[1];
    const float* alpha = (const float*)d_in[2];
    const float* sw = (const float*)d_in[3];
    const float* pot = (const float*)d_in[4];
    float* out = (float*)d_out;
    const int rows = in_sizes[0] / DD;   // B*S = 8192
    cayley_kernel<<<dim3(rows / 4), dim3(256), 0, stream>>>(psi_r, psi_i, alpha, sw, pot, out);
}

// Round 21
// 39.545 us; speedup vs baseline: 1.0538x; 1.0240x over previous
//
#include <hip/hip_runtime.h>

#define DD 1024
#define IMGF 2176                 // row image floats: [0,40) Lhalo | [40,2088) row | [2088,2128) Rhalo | pad
// K=2 minimax-Cayley (validated r17): y1 = rot + C1*(H rot)^perp ; x = rot + C2*(H y1)^perp
#define C1_F 0.0498693f
#define C2_F 0.0975700f

typedef float f2 __attribute__((ext_vector_type(2)));

// d -= w * v, w = uniform SGPR pair {w,w} (forced VOP3P packed FMA)
__device__ __forceinline__ void pk_fnma_s(f2& d, unsigned long long w, f2 v) {
    asm("v_pk_fma_f32 %0, %1, %2, %0 neg_lo:[1,0,0] neg_hi:[1,0,0]"
        : "+v"(d) : "s"(w), "v"(v));
}

// XOR swizzle (validated r17/r20): involution, 16B-align preserved, commutes
// with multiples of 128 floats (+-1024 chunk offset, +-2048 halo shifts).
__device__ __forceinline__ int swzf(int f) { return f ^ (((f >> 5) & 3) << 2); }

__device__ __forceinline__ void fence_lds() {
    asm volatile("s_waitcnt lgkmcnt(0)" ::: "memory");
}

// Wave64 sum via DPP; total broadcast via readlane 63. No barrier.
__device__ __forceinline__ float wave_total(float v) {
    int b;
    b = __builtin_amdgcn_update_dpp(0, __float_as_int(v), 0x111, 0xf, 0xf, true); v += __int_as_float(b);
    b = __builtin_amdgcn_update_dpp(0, __float_as_int(v), 0x112, 0xf, 0xf, true); v += __int_as_float(b);
    b = __builtin_amdgcn_update_dpp(0, __float_as_int(v), 0x114, 0xf, 0xf, true); v += __int_as_float(b);
    b = __builtin_amdgcn_update_dpp(0, __float_as_int(v), 0x118, 0xf, 0xf, true); v += __int_as_float(b);
    b = __builtin_amdgcn_update_dpp(0, __float_as_int(v), 0x142, 0xa, 0xf, true); v += __int_as_float(b);
    b = __builtin_amdgcn_update_dpp(0, __float_as_int(v), 0x143, 0xc, 0xf, true); v += __int_as_float(b);
    return __int_as_float(__builtin_amdgcn_readlane(__float_as_int(v), 63));
}

// tap -> weight index, -1 if none. Constant-folds under full unroll.
__device__ constexpr int tapidx(int a) {
    return a == 1 ? 0 : a == 2 ? 1 : a == 3 ? 2 : a == 4 ? 3 : a == 5 ? 4 :
           a == 6 ? 5 : a == 8 ? 6 : a == 10 ? 7 : a == 12 ? 8 :
           a == 16 ? 9 : a == 20 ? 10 : -1;
}

// Scatter-accumulate H on one 8-complex chunk (centers from regs, neighbors
// streamed from LDS one b128 at a time -> small transient window).
__device__ __forceinline__ void hmat8s(const float* lds, const int raL[10], const int raR[10],
                                       int cOff, const unsigned long long wp[11],
                                       const float* diag, const f2* pc, f2* H) {
    constexpr int taps[11] = {1, 2, 3, 4, 5, 6, 8, 10, 12, 16, 20};
#pragma unroll
    for (int i = 0; i < 8; ++i) {
        f2 acc = f2{diag[i] * pc[i].x, diag[i] * pc[i].y};
#pragma unroll
        for (int j = 0; j < 11; ++j) {              // center-resident taps
            const int n = i - taps[j];
            if (n >= 0) pk_fnma_s(acc, wp[j], pc[n]);
            const int m = i + taps[j];
            if (m <= 7) pk_fnma_s(acc, wp[j], pc[m]);
        }
        H[i] = acc;
    }
#pragma unroll
    for (int k = 0; k < 10; ++k) {                  // left window, complex -20+2k
        float4 q = *reinterpret_cast<const float4*>(&lds[raL[k] + cOff]);
        f2 c0 = f2{q.x, q.y}, c1 = f2{q.z, q.w};
#pragma unroll
        for (int i = 0; i < 8; ++i) {
            const int a0 = i + 20 - 2 * k, a1 = a0 - 1;
            if (tapidx(a0) >= 0) pk_fnma_s(H[i], wp[tapidx(a0)], c0);
            if (a1 >= 1 && tapidx(a1) >= 0) pk_fnma_s(H[i], wp[tapidx(a1)], c1);
        }
    }
#pragma unroll
    for (int k = 0; k < 10; ++k) {                  // right window, complex 8+2k
        float4 q = *reinterpret_cast<const float4*>(&lds[raR[k] + cOff]);
        f2 c0 = f2{q.x, q.y}, c1 = f2{q.z, q.w};
#pragma unroll
        for (int i = 0; i < 8; ++i) {
            const int a0 = 8 + 2 * k - i, a1 = a0 + 1;
            if (tapidx(a0) >= 0) pk_fnma_s(H[i], wp[tapidx(a0)], c0);
            if (tapidx(a1) >= 0) pk_fnma_s(H[i], wp[tapidx(a1)], c1);
        }
    }
}

__global__ void __launch_bounds__(64, 4)
cayley_kernel(const float* __restrict__ psi_r, const float* __restrict__ psi_i,
              const float* __restrict__ alpha, const float* __restrict__ sw,
              const float* __restrict__ potential, float* __restrict__ out) {
    __shared__ __align__(16) float lds[IMGF];   // one wave, one row, no barriers

    const int l = threadIdx.x;     // 0..63
    const int row = blockIdx.x;

    const float w0 = sw[0], w1 = sw[1], w2 = sw[2];
    const float cwv[11] = {w0, w0 + w1, w0, w0 + w1 + w2, w0, w1, w1 + w2, w1, w2, w2, w2};
    const float dadd = 10.0f * (w0 + w1 + w2);

    unsigned long long wp[11];
#pragma unroll
    for (int j = 0; j < 11; ++j) {
        const unsigned int b = __builtin_amdgcn_readfirstlane(__float_as_uint(cwv[j]));
        wp[j] = ((unsigned long long)b << 32) | b;
    }

    // Addresses (float idx). Chunk0 windows; chunk1 = +1024 imm (swizzle commutes).
    const int fl = 16 * l;
    int wa[4], raL[10], raR[10];
#pragma unroll
    for (int j = 0; j < 4; ++j) wa[j] = swzf(fl + 40 + 4 * j);
#pragma unroll
    for (int k = 0; k < 5; ++k) {
        raL[k] = swzf(fl + 4 * k);            raL[5 + k] = swzf(fl + 20 + 4 * k);
        raR[k] = swzf(fl + 56 + 4 * k);       raR[5 + k] = swzf(fl + 76 + 4 * k);
    }
    const int jminL = (l == 61) ? 2 : 0;                       // left halo: lanes 61..63 (chunk1)
    const int jmaxR = (l < 2) ? 4 : ((l == 2) ? 2 : 0);        // right halo: lanes 0..2 (chunk0)

    // --- global loads: chunk0 = [8l,8l+8), chunk1 = +512 complex ---
    const size_t g0 = (size_t)row * DD + 8 * l;
    f2 cur[16];
    float diag[16], alv[16];
#pragma unroll
    for (int c = 0; c < 2; ++c) {
        const size_t g = g0 + 512 * c;
#pragma unroll
        for (int j = 0; j < 2; ++j) {
            float4 a = *reinterpret_cast<const float4*>(psi_r + g + 4 * j);
            float4 b = *reinterpret_cast<const float4*>(psi_i + g + 4 * j);
            float4 d = *reinterpret_cast<const float4*>(potential + 8 * l + 512 * c + 4 * j);
            float4 e = *reinterpret_cast<const float4*>(alpha + 8 * l + 512 * c + 4 * j);
            const int o = 8 * c + 4 * j;
            cur[o + 0] = f2{a.x, b.x}; cur[o + 1] = f2{a.y, b.y};
            cur[o + 2] = f2{a.z, b.z}; cur[o + 3] = f2{a.w, b.w};
            diag[o] = d.x + dadd; diag[o + 1] = d.y + dadd;
            diag[o + 2] = d.z + dadd; diag[o + 3] = d.w + dadd;
            alv[o] = e.x; alv[o + 1] = e.y; alv[o + 2] = e.z; alv[o + 3] = e.w;
        }
    }

    // --- intensity mean: pure wave reduction ---
    float isum = 0.f;
#pragma unroll
    for (int i = 0; i < 16; ++i) isum += cur[i].x * cur[i].x + cur[i].y * cur[i].y;
    const float inv_mean = 1.0f / (wave_total(isum) * (1.0f / DD) + 1e-8f);

    // --- nonlinear phase rotation (in place) ---
#pragma unroll
    for (int i = 0; i < 16; ++i) {
        const float ph = alv[i] * ((cur[i].x * cur[i].x + cur[i].y * cur[i].y) * inv_mean);
        float s, cc;
        __sincosf(ph, &s, &cc);
        cur[i] = f2{cur[i].x * cc - cur[i].y * s, cur[i].x * s + cur[i].y * cc};
    }

    // --- publish rot (both chunks + halos); wave-private fence only ---
#pragma unroll
    for (int j = 0; j < 4; ++j) {
        float4 a0 = make_float4(cur[2 * j].x, cur[2 * j].y, cur[2 * j + 1].x, cur[2 * j + 1].y);
        float4 a1 = make_float4(cur[8 + 2 * j].x, cur[8 + 2 * j].y, cur[9 + 2 * j].x, cur[9 + 2 * j].y);
        *reinterpret_cast<float4*>(&lds[wa[j]]) = a0;
        *reinterpret_cast<float4*>(&lds[wa[j] + 1024]) = a1;
        if (l >= 61 && j >= jminL) *reinterpret_cast<float4*>(&lds[wa[j] - 1024]) = a1;
        if (j < jmaxR)             *reinterpret_cast<float4*>(&lds[wa[j] + 2048]) = a0;
    }
    fence_lds();

    // --- matvec 1: H(rot); y1 = rot + C1*H^perp ---
    f2 y[16], H[16];
    hmat8s(lds, raL, raR, 0,    wp, diag,     cur,     H);
    hmat8s(lds, raL, raR, 1024, wp, diag + 8, cur + 8, H + 8);
#pragma unroll
    for (int i = 0; i < 16; ++i)
        y[i] = f2{cur[i].x + C1_F * H[i].y, cur[i].y - C1_F * H[i].x};

    // --- publish y1 (overwrites rot; DS ops in-order per wave => no WAR) ---
#pragma unroll
    for (int j = 0; j < 4; ++j) {
        float4 a0 = make_float4(y[2 * j].x, y[2 * j].y, y[2 * j + 1].x, y[2 * j + 1].y);
        float4 a1 = make_float4(y[8 + 2 * j].x, y[8 + 2 * j].y, y[9 + 2 * j].x, y[9 + 2 * j].y);
        *reinterpret_cast<float4*>(&lds[wa[j]]) = a0;
        *reinterpret_cast<float4*>(&lds[wa[j] + 1024]) = a1;
        if (l >= 61 && j >= jminL) *reinterpret_cast<float4*>(&lds[wa[j] - 1024]) = a1;
        if (j < jmaxR)             *reinterpret_cast<float4*>(&lds[wa[j] + 2048]) = a0;
    }
    fence_lds();

    // --- matvec 2: H(y1); x = rot + C2*H^perp; write out ---
    hmat8s(lds, raL, raR, 0,    wp, diag,     y,     H);
    hmat8s(lds, raL, raR, 1024, wp, diag + 8, y + 8, H + 8);

    float* op = out + 2 * g0;
#pragma unroll
    for (int c = 0; c < 2; ++c) {
#pragma unroll
        for (int j = 0; j < 4; ++j) {
            const int o = 8 * c + 2 * j;
            const f2 x0 = f2{cur[o].x + C2_F * H[o].y, cur[o].y - C2_F * H[o].x};
            const f2 x1 = f2{cur[o + 1].x + C2_F * H[o + 1].y, cur[o + 1].y - C2_F * H[o + 1].x};
            *reinterpret_cast<float4*>(op + 1024 * c + 4 * j) = make_float4(x0.x, x0.y, x1.x, x1.y);
        }
    }
}

extern "C" void kernel_launch(void* const* d_in, const int* in_sizes, int n_in,
                              void* d_out, int out_size, void* d_ws, size_t ws_size,
                              hipStream_t stream) {
    const float* psi_r = (const float*)d_in[0];
    const float* psi_i = (const float*)d_in[1];
    const float* alpha = (const float*)d_in[2];
    const float* sw = (const float*)d_in[3];
    const float* pot = (const float*)d_in[4];
    float* out = (float*)d_out;
    const int rows = in_sizes[0] / DD;   // B*S = 8192
    cayley_kernel<<<dim3(rows), dim3(64), 0, stream>>>(psi_r, psi_i, alpha, sw, pot, out);
}